// Round 16
// baseline (94.524 us; speedup 1.0000x reference)
//
#include <hip/hip_runtime.h>

// ---------------------------------------------------------------------------
// DagLinkExtractor: B=8, N=1024, HID=1024, NH=4, HD=256
// out[b,i,j] = log Σ_h exp(s_h/1)·ec[b,h,i]  (alive), else -1e9
//   s = (Q_h . K_h)/16 (1/16 applied in exp arg); ec = exp(log_gate)/Z
// Compute-twice, no P materialization:
//   k_prep2 -> k_gemm (fp8 mfma_scale) -> k_z (Z partials) -> k_c (ec)
//   -> k_out (fused 4-head score recompute + log-combine, writes out).
// ---------------------------------------------------------------------------

typedef __attribute__((ext_vector_type(4))) float f32x4;
typedef __attribute__((ext_vector_type(16))) float f32x16;
typedef __attribute__((ext_vector_type(8))) int i32x8;

#define LB __launch_bounds__(256)

__device__ __forceinline__ void gld16(const void* g, void* l) {
    __builtin_amdgcn_global_load_lds(
        (const __attribute__((address_space(1))) unsigned int*)g,
        (__attribute__((address_space(3))) unsigned int*)l, 16, 0, 0);
}

// ---- 1. fused prep: X8=fp8(feat), lgA=log_softmax(feat@Wg+bg), W8=fp8(16*W^T)
__global__ LB void k_prep2(const float* __restrict__ feat, const float* __restrict__ Wg,
                           const float* __restrict__ bg, const float* __restrict__ Wq,
                           const float* __restrict__ Wk, char* __restrict__ X8,
                           float* __restrict__ lgA, char* __restrict__ W8) {
    __shared__ float tile[32][33];
    const int t = threadIdx.x;
    if (blockIdx.x < 2048) {                       // gates + X convert (fp8)
        int row = blockIdx.x * 4 + (t >> 6);
        int lane = t & 63;
        const float* f = feat + (size_t)row * 1024;
        float g0 = 0.f, g1 = 0.f, g2 = 0.f, g3 = 0.f;
#pragma unroll
        for (int tt = 0; tt < 4; ++tt) {
            int k = tt * 256 + lane * 4;
            float4 x = *(const float4*)&f[k];
            float4 w0 = *(const float4*)&Wg[(k + 0) * 4];
            float4 w1 = *(const float4*)&Wg[(k + 1) * 4];
            float4 w2 = *(const float4*)&Wg[(k + 2) * 4];
            float4 w3 = *(const float4*)&Wg[(k + 3) * 4];
            g0 += x.x * w0.x + x.y * w1.x + x.z * w2.x + x.w * w3.x;
            g1 += x.x * w0.y + x.y * w1.y + x.z * w2.y + x.w * w3.y;
            g2 += x.x * w0.z + x.y * w1.z + x.z * w2.z + x.w * w3.z;
            g3 += x.x * w0.w + x.y * w1.w + x.z * w2.w + x.w * w3.w;
            unsigned u01 = (unsigned)__builtin_amdgcn_cvt_pk_fp8_f32(x.x, x.y, 0, false);
            unsigned u23 = (unsigned)__builtin_amdgcn_cvt_pk_fp8_f32(x.z, x.w, 0, false);
            *(unsigned*)&X8[(size_t)row * 1024 + k] = (u01 & 0xffffu) | (u23 << 16);
        }
#pragma unroll
        for (int off = 32; off; off >>= 1) {
            g0 += __shfl_xor(g0, off); g1 += __shfl_xor(g1, off);
            g2 += __shfl_xor(g2, off); g3 += __shfl_xor(g3, off);
        }
        g0 += bg[0]; g1 += bg[1]; g2 += bg[2]; g3 += bg[3];
        float m = fmaxf(fmaxf(g0, g1), fmaxf(g2, g3));
        float s = __expf(g0 - m) + __expf(g1 - m) + __expf(g2 - m) + __expf(g3 - m);
        float ls = m + __logf(s);
        if (lane == 0) {
            float4 o = {g0 - ls, g1 - ls, g2 - ls, g3 - ls};
            *(float4*)&lgA[row * 4] = o;
        }
    } else {                                       // W transpose + x16 + fp8
        int bid = blockIdx.x - 2048;
        int n0 = (bid & 63) * 32, k0 = (bid >> 6) * 32;
        const float* W = (n0 < 1024) ? Wq : Wk;
        int nb = n0 & 1023;
        int tx = t & 31, ty = t >> 5;
#pragma unroll
        for (int jj = 0; jj < 4; ++jj) {
            int k = ty + jj * 8;
            tile[k][tx] = W[(size_t)(k0 + k) * 1024 + nb + tx];
        }
        __syncthreads();
#pragma unroll
        for (int jj = 0; jj < 4; ++jj) {
            int n = ty + jj * 8;
            float w16 = tile[tx][n] * 16.f;
            W8[(size_t)(n0 + n) * 1024 + k0 + tx] =
                (char)(__builtin_amdgcn_cvt_pk_fp8_f32(w16, w16, 0, false) & 0xff);
        }
    }
}

// ---- 2. k_gemm MX-fp8: 256x256 tile, BK=64, 3-buffer pipeline ---------------
__device__ __forceinline__ i32x8 ldfrag8(const char* tb, int row, int khalf) {
    const int sw = (row >> 1) & 3;
    uint4 lo = *(const uint4*)&tb[row * 64 + (((khalf * 2 + 0) ^ sw) * 16)];
    uint4 hi = *(const uint4*)&tb[row * 64 + (((khalf * 2 + 1) ^ sw) * 16)];
    i32x8 r;
    r[0] = lo.x; r[1] = lo.y; r[2] = lo.z; r[3] = lo.w;
    r[4] = hi.x; r[5] = hi.y; r[6] = hi.z; r[7] = hi.w;
    return r;
}

__global__ __launch_bounds__(512, 2) void k_gemm(const char* __restrict__ X8,
                                                 const char* __restrict__ W8,
                                                 const float* __restrict__ bq,
                                                 const float* __restrict__ bk,
                                                 char* __restrict__ Q8,
                                                 char* __restrict__ K8) {
    __shared__ char SM[3][32768];                  // 3 x (A 16K + B 16K) = 96 KB
    const int t = threadIdx.x;
    const int lane = t & 63, wid = t >> 6;
    const int wr = wid >> 2, wc = wid & 3;         // 2 x 4 waves
    const int l31 = lane & 31, khalf = lane >> 5;
    const int wgid = (blockIdx.x & 7) * 32 + (blockIdx.x >> 3);
    const int m0t = (wgid >> 3) * 256, n0t = (wgid & 7) * 256;

    f32x16 acc[4][2] = {};

#define SGA(q, k1, dst)                                                         \
    { int s_ = (q) * 512 + t; int tr_ = s_ >> 2, c_ = s_ & 3;                   \
      gld16(&X8[(size_t)(m0t + tr_) * 1024 + (k1) + (((c_) ^ ((tr_ >> 1) & 3)) * 16)], \
            (dst) + s_ * 16); }
#define SGB(q, k1, dst)                                                         \
    { int s_ = (q) * 512 + t; int tr_ = s_ >> 2, c_ = s_ & 3;                   \
      gld16(&W8[(size_t)(n0t + tr_) * 1024 + (k1) + (((c_) ^ ((tr_ >> 1) & 3)) * 16)], \
            (dst) + 16384 + s_ * 16); }

    SGA(0, 0, SM[0]); SGA(1, 0, SM[0]); SGB(0, 0, SM[0]); SGB(1, 0, SM[0]);
    SGA(0, 64, SM[1]); SGA(1, 64, SM[1]); SGB(0, 64, SM[1]); SGB(1, 64, SM[1]);
    asm volatile("s_waitcnt vmcnt(4)" ::: "memory");
    __builtin_amdgcn_sched_barrier(0);
    __builtin_amdgcn_s_barrier();

    for (int kt = 0; kt < 16; ++kt) {
        const char* buf = SM[kt % 3];
        char* bufn = SM[(kt + 2) % 3];
        if (kt < 14) {
            const int k2 = (kt + 2) * 64;
            SGA(0, k2, bufn); SGA(1, k2, bufn); SGB(0, k2, bufn); SGB(1, k2, bufn);
        }
        i32x8 aF[4], bF[2];
#pragma unroll
        for (int rt = 0; rt < 4; ++rt)
            aF[rt] = ldfrag8(buf, wr * 128 + rt * 32 + l31, khalf);
#pragma unroll
        for (int ct = 0; ct < 2; ++ct)
            bF[ct] = ldfrag8(buf + 16384, wc * 64 + ct * 32 + l31, khalf);
        __builtin_amdgcn_s_setprio(1);
#pragma unroll
        for (int rt = 0; rt < 4; ++rt)
#pragma unroll
            for (int ct = 0; ct < 2; ++ct)
                acc[rt][ct] = __builtin_amdgcn_mfma_scale_f32_32x32x64_f8f6f4(
                    aF[rt], bF[ct], acc[rt][ct], 0, 0, 0, 127, 0, 127);
        __builtin_amdgcn_s_setprio(0);
        if (kt < 14)       asm volatile("s_waitcnt vmcnt(4)" ::: "memory");
        else if (kt == 14) asm volatile("s_waitcnt vmcnt(0)" ::: "memory");
        __builtin_amdgcn_sched_barrier(0);
        __builtin_amdgcn_s_barrier();
    }
#undef SGA
#undef SGB

    // epilogue: acc/16 (undo W x16) + bias; fp8 out in head layout
#pragma unroll
    for (int rt = 0; rt < 4; ++rt) {
#pragma unroll
        for (int ct = 0; ct < 2; ++ct) {
            const int col = n0t + wc * 64 + ct * 32 + l31;
            const float bias = (col < 1024) ? bq[col] : bk[col - 1024];
            char* dst = (col < 1024) ? Q8 : K8;
            const int h = (col >> 8) & 3, d = col & 255;
#pragma unroll
            for (int reg = 0; reg < 16; ++reg) {
                const int rin = (reg & 3) + 8 * (reg >> 2) + 4 * khalf;
                const int grow = m0t + wr * 128 + rt * 32 + rin;
                const int b_ = grow >> 10, i_ = grow & 1023;
                float v = acc[rt][ct][reg] * 0.0625f + bias;
                dst[((size_t)(b_ * 4 + h) * 1024 + i_) * 256 + d] =
                    (char)(__builtin_amdgcn_cvt_pk_fp8_f32(v, v, 0, false) & 0xff);
            }
        }
    }
}

// shared fragment loader for the [128][256B] score tiles (granule swz g^(row&15))
__device__ __forceinline__ i32x8 ldsc(const char* tb, int row, int p0) {
    const int sw = row & 15;
    uint4 lo = *(const uint4*)&tb[row * 256 + (((p0 + 0) ^ sw) * 16)];
    uint4 hi = *(const uint4*)&tb[row * 256 + (((p0 + 1) ^ sw) * 16)];
    i32x8 r;
    r[0] = lo.x; r[1] = lo.y; r[2] = lo.z; r[3] = lo.w;
    r[4] = hi.x; r[5] = hi.y; r[6] = hi.z; r[7] = hi.w;
    return r;
}

// ---- 3. k_z: Z partials only (fp8 score GEMM, upper-tri 128² tiles) ---------
// grid 1152 = 32 bh x 36 tiles, 256 thr; Zp[jt8*2+wc][bh][i] masked row sums.
__global__ __launch_bounds__(256, 2) void k_z(const char* __restrict__ Q8,
                                              const char* __restrict__ K8,
                                              const int* __restrict__ vm,
                                              float* __restrict__ Zp) {
    __shared__ char SMEM[65536];                   // A 32K + B 32K
    char* As = SMEM;
    char* Bs = SMEM + 32768;
    const int t = threadIdx.x;
    const int lane = t & 63, wid = t >> 6;
    const int wr = wid >> 1, wc = wid & 1;
    const int l31 = lane & 31, khalf = lane >> 5;
    const int gidx = (blockIdx.x & 7) * 144 + (blockIdx.x >> 3);
    const int bh = gidx / 36, tt = gidx % 36;
    const int it8 = (tt >= 8) + (tt >= 15) + (tt >= 21) + (tt >= 26)
                  + (tt >= 30) + (tt >= 33) + (tt >= 35);
    const int base8 = (it8 == 0) ? 0 : (it8 == 1) ? 8 : (it8 == 2) ? 15
                    : (it8 == 3) ? 21 : (it8 == 4) ? 26 : (it8 == 5) ? 30
                    : (it8 == 6) ? 33 : 35;
    const int jt8 = it8 + (tt - base8);
    const int b = bh >> 2;
    const char* Qp = Q8 + ((size_t)bh << 18);
    const char* Kp = K8 + ((size_t)bh << 18);

#pragma unroll
    for (int pass = 0; pass < 8; ++pass) {
        int s_ = pass * 256 + t;
        int row = s_ >> 4, g = s_ & 15;
        gld16(&Qp[(size_t)(it8 * 128 + row) * 256 + ((g ^ (row & 15)) * 16)],
              As + s_ * 16);
    }
#pragma unroll
    for (int pass = 0; pass < 8; ++pass) {
        int s_ = pass * 256 + t;
        int row = s_ >> 4, g = s_ & 15;
        gld16(&Kp[(size_t)(jt8 * 128 + row) * 256 + ((g ^ (row & 15)) * 16)],
              Bs + s_ * 16);
    }
    asm volatile("s_waitcnt vmcnt(0)" ::: "memory");
    __builtin_amdgcn_sched_barrier(0);
    __builtin_amdgcn_s_barrier();

    f32x16 acc[2][2] = {};
#pragma unroll
    for (int ks = 0; ks < 4; ++ks) {
        const int p0 = ks * 4 + khalf * 2;
        i32x8 aF[2], bF[2];
#pragma unroll
        for (int rt = 0; rt < 2; ++rt)
            aF[rt] = ldsc(As, wr * 64 + rt * 32 + l31, p0);
#pragma unroll
        for (int ct = 0; ct < 2; ++ct)
            bF[ct] = ldsc(Bs, wc * 64 + ct * 32 + l31, p0);
        __builtin_amdgcn_s_setprio(1);
#pragma unroll
        for (int rt = 0; rt < 2; ++rt)
#pragma unroll
            for (int ct = 0; ct < 2; ++ct)
                acc[rt][ct] = __builtin_amdgcn_mfma_scale_f32_32x32x64_f8f6f4(
                    aF[rt], bF[ct], acc[rt][ct], 0, 0, 0, 127, 0, 127);
        __builtin_amdgcn_s_setprio(0);
    }

    const int rowbase = it8 * 128 + wr * 64;
    const int colbase = jt8 * 128 + wc * 64;
    int vmv[2];
#pragma unroll
    for (int ct = 0; ct < 2; ++ct)
        vmv[ct] = vm[(b << 10) + colbase + ct * 32 + l31];
    float zacc[2][16] = {};
#pragma unroll
    for (int rt = 0; rt < 2; ++rt)
#pragma unroll
        for (int ct = 0; ct < 2; ++ct) {
            const int col = colbase + ct * 32 + l31;
#pragma unroll
            for (int reg = 0; reg < 16; ++reg) {
                const int rin = (reg & 3) + 8 * (reg >> 2) + 4 * khalf;
                const int row = rowbase + rt * 32 + rin;
                float e = __expf(acc[rt][ct][reg] * 0.0625f);
                zacc[rt][reg] += (vmv[ct] && (col > row)) ? e : 0.f;
            }
        }
#pragma unroll
    for (int rt = 0; rt < 2; ++rt)
#pragma unroll
        for (int reg = 0; reg < 16; ++reg) {
            zacc[rt][reg] += __shfl_xor(zacc[rt][reg], 1);
            zacc[rt][reg] += __shfl_xor(zacc[rt][reg], 2);
            zacc[rt][reg] += __shfl_xor(zacc[rt][reg], 4);
            zacc[rt][reg] += __shfl_xor(zacc[rt][reg], 8);
            zacc[rt][reg] += __shfl_xor(zacc[rt][reg], 16);
        }
    if (l31 == 0) {
        float* Zs = Zp + (size_t)(jt8 * 2 + wc) * 32768 + bh * 1024;
#pragma unroll
        for (int rt = 0; rt < 2; ++rt)
#pragma unroll
            for (int reg = 0; reg < 16; ++reg) {
                const int rin = (reg & 3) + 8 * (reg >> 2) + 4 * khalf;
                Zs[rowbase + rt * 32 + rin] = zacc[rt][reg];
            }
    }
}

// ---- 4. k_c: ecF[(b,i)][h] = exp(lg)/Z (slices sl >= (i>>7)*2 are written) --
__global__ LB void k_c(const float* __restrict__ lgA, const float* __restrict__ Zp,
                       float* __restrict__ ecF) {
    int idx = blockIdx.x * 256 + threadIdx.x;      // 8192 = b*1024+i
    int b = idx >> 10, i = idx & 1023;
    int sl0 = (i >> 7) * 2;
    float4 lg = *(const float4*)&lgA[idx * 4];
    float4 o;
#pragma unroll
    for (int h = 0; h < 4; ++h) {
        int base = (b * 4 + h) * 1024 + i;
        float Zv = 0.f;
        for (int sl = sl0; sl < 16; ++sl) Zv += Zp[sl * 32768 + base];
        float lgv = (h == 0) ? lg.x : (h == 1) ? lg.y : (h == 2) ? lg.z : lg.w;
        float e = (Zv > 0.f) ? __expf(lgv) / Zv : 0.f;
        if (h == 0) o.x = e; else if (h == 1) o.y = e;
        else if (h == 2) o.z = e; else o.w = e;
    }
    *(float4*)&ecF[idx * 4] = o;
}

// ---- 5. k_out: fused 4-head score recompute + log-combine -------------------
// grid 512 = 8 b (XCD-chunked) x 64 (it8,jt8); 256 thr (2x2 waves, 128² tile).
// Lower-tri tiles: -1e9 fill, exit. Else loop h: stage Q/K tile (64 KB, single
// buffer), mfma_scale x16/wave, aex += exp(s/16)*ec[h]; write log(aex).
__global__ __launch_bounds__(256, 2) void k_out(const char* __restrict__ Q8,
                                                const char* __restrict__ K8,
                                                const int* __restrict__ vm,
                                                const float* __restrict__ ecF,
                                                float* __restrict__ out) {
    __shared__ char SMEM[65536];                   // A 32K + B 32K
    __shared__ float ecL[4][128];
    char* As = SMEM;
    char* Bs = SMEM + 32768;
    const int t = threadIdx.x;
    const int lane = t & 63, wid = t >> 6;
    const int wr = wid >> 1, wc = wid & 1;
    const int l31 = lane & 31, khalf = lane >> 5;
    const int b = blockIdx.x & 7;                  // one b per XCD
    const int tile = blockIdx.x >> 3;
    const int it8 = tile >> 3, jt8 = tile & 7;
    const int i0blk = it8 * 128, j0blk = jt8 * 128;

    if (jt8 < it8) {                               // strictly lower: fill, exit
        const float4 m4 = {-1.0e9f, -1.0e9f, -1.0e9f, -1.0e9f};
#pragma unroll
        for (int pass = 0; pass < 16; ++pass) {
            int s_ = pass * 256 + t;
            int r = s_ >> 5, cg = s_ & 31;
            *(float4*)&out[((size_t)((b << 10) + i0blk + r) << 10) + j0blk + cg * 4] = m4;
        }
        return;
    }

    if (t < 128) {                                 // stage ec for this i-block
        float4 e = *(const float4*)&ecF[((b << 10) + i0blk + t) * 4];
        ecL[0][t] = e.x; ecL[1][t] = e.y; ecL[2][t] = e.z; ecL[3][t] = e.w;
    }

    float aex[2][2][16] = {};
    for (int h = 0; h < 4; ++h) {
        const char* Qp = Q8 + ((size_t)(b * 4 + h) << 18);
        const char* Kp = K8 + ((size_t)(b * 4 + h) << 18);
#pragma unroll
        for (int pass = 0; pass < 8; ++pass) {
            int s_ = pass * 256 + t;
            int row = s_ >> 4, g = s_ & 15;
            gld16(&Qp[(size_t)(i0blk + row) * 256 + ((g ^ (row & 15)) * 16)],
                  As + s_ * 16);
        }
#pragma unroll
        for (int pass = 0; pass < 8; ++pass) {
            int s_ = pass * 256 + t;
            int row = s_ >> 4, g = s_ & 15;
            gld16(&Kp[(size_t)(j0blk + row) * 256 + ((g ^ (row & 15)) * 16)],
                  Bs + s_ * 16);
        }
        asm volatile("s_waitcnt vmcnt(0)" ::: "memory");
        __builtin_amdgcn_sched_barrier(0);
        __builtin_amdgcn_s_barrier();

        f32x16 acc[2][2] = {};
#pragma unroll
        for (int ks = 0; ks < 4; ++ks) {
            const int p0 = ks * 4 + khalf * 2;
            i32x8 aF[2], bF[2];
#pragma unroll
            for (int rt = 0; rt < 2; ++rt)
                aF[rt] = ldsc(As, wr * 64 + rt * 32 + l31, p0);
#pragma unroll
            for (int ct = 0; ct < 2; ++ct)
                bF[ct] = ldsc(Bs, wc * 64 + ct * 32 + l31, p0);
            __builtin_amdgcn_s_setprio(1);
#pragma unroll
            for (int rt = 0; rt < 2; ++rt)
#pragma unroll
                for (int ct = 0; ct < 2; ++ct)
                    acc[rt][ct] = __builtin_amdgcn_mfma_scale_f32_32x32x64_f8f6f4(
                        aF[rt], bF[ct], acc[rt][ct], 0, 0, 0, 127, 0, 127);
            __builtin_amdgcn_s_setprio(0);
        }
#pragma unroll
        for (int rt = 0; rt < 2; ++rt)
#pragma unroll
            for (int ct = 0; ct < 2; ++ct)
#pragma unroll
                for (int reg = 0; reg < 16; ++reg) {
                    const int rin = (reg & 3) + 8 * (reg >> 2) + 4 * khalf;
                    const int rloc = wr * 64 + rt * 32 + rin;
                    aex[rt][ct][reg] += __expf(acc[rt][ct][reg] * 0.0625f)
                                        * ecL[h][rloc];
                }
        __syncthreads();                           // frag reads done before re-stage
    }

    // epilogue: masked log, coalesced stores (32 lanes = 128B row segment)
    const int rowbase = wr * 64;
    const int colbase = j0blk + wc * 64;
    int vmv[2];
#pragma unroll
    for (int ct = 0; ct < 2; ++ct)
        vmv[ct] = vm[(b << 10) + colbase + ct * 32 + l31];
#pragma unroll
    for (int rt = 0; rt < 2; ++rt)
#pragma unroll
        for (int ct = 0; ct < 2; ++ct) {
            const int col = colbase + ct * 32 + l31;
#pragma unroll
            for (int reg = 0; reg < 16; ++reg) {
                const int rin = (reg & 3) + 8 * (reg >> 2) + 4 * khalf;
                const int gi = i0blk + rowbase + rt * 32 + rin;
                float o = (vmv[ct] && (col > gi)) ? __logf(aex[rt][ct][reg])
                                                  : -1.0e9f;
                out[((size_t)((b << 10) + gi) << 10) + col] = o;
            }
        }
}

// ---------------------------------------------------------------------------
extern "C" void kernel_launch(void* const* d_in, const int* in_sizes, int n_in,
                              void* d_out, int out_size, void* d_ws, size_t ws_size,
                              hipStream_t stream) {
    const float* features = (const float*)d_in[0];
    const int*   vmask    = (const int*)d_in[1];
    const float* Wq       = (const float*)d_in[2];
    const float* bq       = (const float*)d_in[3];
    const float* Wk       = (const float*)d_in[4];
    const float* bk       = (const float*)d_in[5];
    const float* Wg       = (const float*)d_in[6];
    const float* bg       = (const float*)d_in[7];
    float* out = (float*)d_out;

    // ws carve (~31 MB)
    char*  X8  = (char*)d_ws;                  // [8192][1024] fp8
    char*  W8  = X8 + 8388608;                 // [2048][1024] fp8 (x16)
    char*  Q8  = W8 + 2097152;                 // [32 bh][1024][256] fp8 (natural)
    char*  K8  = Q8 + 8388608;                 // [32 bh][1024][256] fp8
    float* lgA = (float*)(K8 + 8388608);       // [8192][4]
    float* Zp  = lgA + 32768;                  // [16 slice][32 bh][1024 i]
    float* ecF = Zp + 524288;                  // [8192][4]

    k_prep2<<<4096, 256, 0, stream>>>(features, Wg, bg, Wq, Wk, X8, lgA, W8);
    k_gemm<<<256, 512, 0, stream>>>(X8, W8, bq, bk, Q8, K8);
    k_z<<<1152, 256, 0, stream>>>(Q8, K8, vmask, Zp);
    k_c<<<32, 256, 0, stream>>>(lgA, Zp, ecF);
    k_out<<<512, 256, 0, stream>>>(Q8, K8, vmask, ecF, out);
}

// Round 17
// 76.418 us; speedup vs baseline: 1.2369x; 1.2369x over previous
//
#include <hip/hip_runtime.h>

// ---------------------------------------------------------------------------
// DagLinkExtractor: B=8, N=1024, HID=1024, NH=4, HD=256
// out[b,i,j] = log Σ_h P[b,h,i,j]·ec[b,h,i]   (alive), else -1e9
//   P = exp(s) stored FP8 E4M3; s = (Q_h . K_h)/16 (1/16 applied in exp arg)
//   ec[b,h,i] = exp(log_gate) / Z,  Z = Σ_{valid j>i} exp(s)
// Full fp8 pipeline: X8/W8 fp8 -> k_gemm (mfma_scale 32x32x64) -> Q8/K8 fp8
// -> k_sc (fp8 score GEMM, single-stage 64KB LDS) -> Pe8 fp8 -> k_final.
// (r15 configuration — best measured at 76.6 µs; r16 compute-twice reverted.)
// ---------------------------------------------------------------------------

typedef __attribute__((ext_vector_type(8))) short bf16x8;
typedef __attribute__((ext_vector_type(4))) short bf16x4;
typedef __attribute__((ext_vector_type(4))) float f32x4;
typedef __attribute__((ext_vector_type(16))) float f32x16;
typedef __attribute__((ext_vector_type(8))) int i32x8;

#define LB __launch_bounds__(256)

__device__ __forceinline__ short f2bf(float f) {
    unsigned u = __float_as_uint(f);
    u += 0x7fffu + ((u >> 16) & 1u);   // RNE
    return (short)(u >> 16);
}

__device__ __forceinline__ void gld16(const void* g, void* l) {
    __builtin_amdgcn_global_load_lds(
        (const __attribute__((address_space(1))) unsigned int*)g,
        (__attribute__((address_space(3))) unsigned int*)l, 16, 0, 0);
}

// ---- 1. fused prep: X8=fp8(feat), lgA=log_softmax(feat@Wg+bg), W8=fp8(16*W^T)
__global__ LB void k_prep2(const float* __restrict__ feat, const float* __restrict__ Wg,
                           const float* __restrict__ bg, const float* __restrict__ Wq,
                           const float* __restrict__ Wk, char* __restrict__ X8,
                           float* __restrict__ lgA, char* __restrict__ W8) {
    __shared__ float tile[32][33];
    const int t = threadIdx.x;
    if (blockIdx.x < 2048) {                       // gates + X convert (fp8)
        int row = blockIdx.x * 4 + (t >> 6);
        int lane = t & 63;
        const float* f = feat + (size_t)row * 1024;
        float g0 = 0.f, g1 = 0.f, g2 = 0.f, g3 = 0.f;
#pragma unroll
        for (int tt = 0; tt < 4; ++tt) {
            int k = tt * 256 + lane * 4;
            float4 x = *(const float4*)&f[k];
            float4 w0 = *(const float4*)&Wg[(k + 0) * 4];
            float4 w1 = *(const float4*)&Wg[(k + 1) * 4];
            float4 w2 = *(const float4*)&Wg[(k + 2) * 4];
            float4 w3 = *(const float4*)&Wg[(k + 3) * 4];
            g0 += x.x * w0.x + x.y * w1.x + x.z * w2.x + x.w * w3.x;
            g1 += x.x * w0.y + x.y * w1.y + x.z * w2.y + x.w * w3.y;
            g2 += x.x * w0.z + x.y * w1.z + x.z * w2.z + x.w * w3.z;
            g3 += x.x * w0.w + x.y * w1.w + x.z * w2.w + x.w * w3.w;
            unsigned u01 = (unsigned)__builtin_amdgcn_cvt_pk_fp8_f32(x.x, x.y, 0, false);
            unsigned u23 = (unsigned)__builtin_amdgcn_cvt_pk_fp8_f32(x.z, x.w, 0, false);
            *(unsigned*)&X8[(size_t)row * 1024 + k] = (u01 & 0xffffu) | (u23 << 16);
        }
#pragma unroll
        for (int off = 32; off; off >>= 1) {
            g0 += __shfl_xor(g0, off); g1 += __shfl_xor(g1, off);
            g2 += __shfl_xor(g2, off); g3 += __shfl_xor(g3, off);
        }
        g0 += bg[0]; g1 += bg[1]; g2 += bg[2]; g3 += bg[3];
        float m = fmaxf(fmaxf(g0, g1), fmaxf(g2, g3));
        float s = __expf(g0 - m) + __expf(g1 - m) + __expf(g2 - m) + __expf(g3 - m);
        float ls = m + __logf(s);
        if (lane == 0) {
            float4 o = {g0 - ls, g1 - ls, g2 - ls, g3 - ls};
            *(float4*)&lgA[row * 4] = o;
        }
    } else {                                       // W transpose + x16 + fp8
        int bid = blockIdx.x - 2048;
        int n0 = (bid & 63) * 32, k0 = (bid >> 6) * 32;
        const float* W = (n0 < 1024) ? Wq : Wk;
        int nb = n0 & 1023;
        int tx = t & 31, ty = t >> 5;
#pragma unroll
        for (int jj = 0; jj < 4; ++jj) {
            int k = ty + jj * 8;
            tile[k][tx] = W[(size_t)(k0 + k) * 1024 + nb + tx];
        }
        __syncthreads();
#pragma unroll
        for (int jj = 0; jj < 4; ++jj) {
            int n = ty + jj * 8;
            float w16 = tile[tx][n] * 16.f;
            W8[(size_t)(n0 + n) * 1024 + k0 + tx] =
                (char)(__builtin_amdgcn_cvt_pk_fp8_f32(w16, w16, 0, false) & 0xff);
        }
    }
}

// ---- 2. k_gemm MX-fp8: 256x256 tile, BK=64, 3-buffer pipeline ---------------
// Epilogue: v = acc/16 + bias (undo W x16); emit Q8/K8 fp8 at NATURAL scale
// (the 1/16 score scale is applied in k_sc's exp argument).
__device__ __forceinline__ i32x8 ldfrag8(const char* tb, int row, int khalf) {
    const int sw = (row >> 1) & 3;
    uint4 lo = *(const uint4*)&tb[row * 64 + (((khalf * 2 + 0) ^ sw) * 16)];
    uint4 hi = *(const uint4*)&tb[row * 64 + (((khalf * 2 + 1) ^ sw) * 16)];
    i32x8 r;
    r[0] = lo.x; r[1] = lo.y; r[2] = lo.z; r[3] = lo.w;
    r[4] = hi.x; r[5] = hi.y; r[6] = hi.z; r[7] = hi.w;
    return r;
}

__global__ __launch_bounds__(512, 2) void k_gemm(const char* __restrict__ X8,
                                                 const char* __restrict__ W8,
                                                 const float* __restrict__ bq,
                                                 const float* __restrict__ bk,
                                                 char* __restrict__ Q8,
                                                 char* __restrict__ K8) {
    __shared__ char SM[3][32768];                  // 3 x (A 16K + B 16K) = 96 KB
    const int t = threadIdx.x;
    const int lane = t & 63, wid = t >> 6;
    const int wr = wid >> 2, wc = wid & 3;         // 2 x 4 waves
    const int l31 = lane & 31, khalf = lane >> 5;
    const int wgid = (blockIdx.x & 7) * 32 + (blockIdx.x >> 3);
    const int m0t = (wgid >> 3) * 256, n0t = (wgid & 7) * 256;

    f32x16 acc[4][2] = {};

#define SGA(q, k1, dst)                                                         \
    { int s_ = (q) * 512 + t; int tr_ = s_ >> 2, c_ = s_ & 3;                   \
      gld16(&X8[(size_t)(m0t + tr_) * 1024 + (k1) + (((c_) ^ ((tr_ >> 1) & 3)) * 16)], \
            (dst) + s_ * 16); }
#define SGB(q, k1, dst)                                                         \
    { int s_ = (q) * 512 + t; int tr_ = s_ >> 2, c_ = s_ & 3;                   \
      gld16(&W8[(size_t)(n0t + tr_) * 1024 + (k1) + (((c_) ^ ((tr_ >> 1) & 3)) * 16)], \
            (dst) + 16384 + s_ * 16); }

    SGA(0, 0, SM[0]); SGA(1, 0, SM[0]); SGB(0, 0, SM[0]); SGB(1, 0, SM[0]);
    SGA(0, 64, SM[1]); SGA(1, 64, SM[1]); SGB(0, 64, SM[1]); SGB(1, 64, SM[1]);
    asm volatile("s_waitcnt vmcnt(4)" ::: "memory");
    __builtin_amdgcn_sched_barrier(0);
    __builtin_amdgcn_s_barrier();

    for (int kt = 0; kt < 16; ++kt) {
        const char* buf = SM[kt % 3];
        char* bufn = SM[(kt + 2) % 3];
        if (kt < 14) {
            const int k2 = (kt + 2) * 64;
            SGA(0, k2, bufn); SGA(1, k2, bufn); SGB(0, k2, bufn); SGB(1, k2, bufn);
        }
        i32x8 aF[4], bF[2];
#pragma unroll
        for (int rt = 0; rt < 4; ++rt)
            aF[rt] = ldfrag8(buf, wr * 128 + rt * 32 + l31, khalf);
#pragma unroll
        for (int ct = 0; ct < 2; ++ct)
            bF[ct] = ldfrag8(buf + 16384, wc * 64 + ct * 32 + l31, khalf);
        __builtin_amdgcn_s_setprio(1);
#pragma unroll
        for (int rt = 0; rt < 4; ++rt)
#pragma unroll
            for (int ct = 0; ct < 2; ++ct)
                acc[rt][ct] = __builtin_amdgcn_mfma_scale_f32_32x32x64_f8f6f4(
                    aF[rt], bF[ct], acc[rt][ct], 0, 0, 0, 127, 0, 127);
        __builtin_amdgcn_s_setprio(0);
        if (kt < 14)       asm volatile("s_waitcnt vmcnt(4)" ::: "memory");
        else if (kt == 14) asm volatile("s_waitcnt vmcnt(0)" ::: "memory");
        __builtin_amdgcn_sched_barrier(0);
        __builtin_amdgcn_s_barrier();
    }
#undef SGA
#undef SGB

    // epilogue: acc/16 (undo W x16) + bias; fp8 out in head layout
#pragma unroll
    for (int rt = 0; rt < 4; ++rt) {
#pragma unroll
        for (int ct = 0; ct < 2; ++ct) {
            const int col = n0t + wc * 64 + ct * 32 + l31;
            const float bias = (col < 1024) ? bq[col] : bk[col - 1024];
            char* dst = (col < 1024) ? Q8 : K8;
            const int h = (col >> 8) & 3, d = col & 255;
#pragma unroll
            for (int reg = 0; reg < 16; ++reg) {
                const int rin = (reg & 3) + 8 * (reg >> 2) + 4 * khalf;
                const int grow = m0t + wr * 128 + rt * 32 + rin;
                const int b_ = grow >> 10, i_ = grow & 1023;
                float v = acc[rt][ct][reg] * 0.0625f + bias;
                dst[((size_t)(b_ * 4 + h) * 1024 + i_) * 256 + d] =
                    (char)(__builtin_amdgcn_cvt_pk_fp8_f32(v, v, 0, false) & 0xff);
            }
        }
    }
}

// ---- 3. k_sc fp8: score GEMM s = Q8 @ K8^T / 16 per bh, upper-tri 128² tiles
// grid 1152 = 32 bh x 36 tiles, 256 thr (4 waves 2x2), 64 KB LDS, 2 blocks/CU.
// Whole 128x256B A/B tiles staged once (granule swizzle g^(row&15), source
// pre-swizzled, LDS linear); 4 K-steps x 4 mfma_scale_32x32x64.
// Epilogue: fp8 Pe + Zp[jt8*2+wc][bh][i] masked row sums (32x32 C layout).
__device__ __forceinline__ i32x8 ldsc(const char* tb, int row, int p0) {
    const int sw = row & 15;
    uint4 lo = *(const uint4*)&tb[row * 256 + (((p0 + 0) ^ sw) * 16)];
    uint4 hi = *(const uint4*)&tb[row * 256 + (((p0 + 1) ^ sw) * 16)];
    i32x8 r;
    r[0] = lo.x; r[1] = lo.y; r[2] = lo.z; r[3] = lo.w;
    r[4] = hi.x; r[5] = hi.y; r[6] = hi.z; r[7] = hi.w;
    return r;
}

__global__ __launch_bounds__(256, 2) void k_sc(const char* __restrict__ Q8,
                                               const char* __restrict__ K8,
                                               const int* __restrict__ vm,
                                               char* __restrict__ Pe8,
                                               float* __restrict__ Zp) {
    __shared__ char SMEM[65536];                   // A 32K + B 32K
    char* As = SMEM;
    char* Bs = SMEM + 32768;
    const int t = threadIdx.x;
    const int lane = t & 63, wid = t >> 6;
    const int wr = wid >> 1, wc = wid & 1;         // 2 x 2 waves
    const int l31 = lane & 31, khalf = lane >> 5;
    const int gidx = (blockIdx.x & 7) * 144 + (blockIdx.x >> 3);  // XCD: 4 bh each
    const int bh = gidx / 36, tt = gidx % 36;
    const int it8 = (tt >= 8) + (tt >= 15) + (tt >= 21) + (tt >= 26)
                  + (tt >= 30) + (tt >= 33) + (tt >= 35);
    const int base8 = (it8 == 0) ? 0 : (it8 == 1) ? 8 : (it8 == 2) ? 15
                    : (it8 == 3) ? 21 : (it8 == 4) ? 26 : (it8 == 5) ? 30
                    : (it8 == 6) ? 33 : 35;
    const int jt8 = it8 + (tt - base8);
    const int b = bh >> 2;
    const char* Qp = Q8 + ((size_t)bh << 18);      // [1024][256] fp8
    const char* Kp = K8 + ((size_t)bh << 18);

    // stage whole tiles: 128 rows x 16 granules each = 8 passes per operand
#pragma unroll
    for (int pass = 0; pass < 8; ++pass) {
        int s_ = pass * 256 + t;
        int row = s_ >> 4, g = s_ & 15;
        gld16(&Qp[(size_t)(it8 * 128 + row) * 256 + ((g ^ (row & 15)) * 16)],
              As + s_ * 16);
    }
#pragma unroll
    for (int pass = 0; pass < 8; ++pass) {
        int s_ = pass * 256 + t;
        int row = s_ >> 4, g = s_ & 15;
        gld16(&Kp[(size_t)(jt8 * 128 + row) * 256 + ((g ^ (row & 15)) * 16)],
              Bs + s_ * 16);
    }
    asm volatile("s_waitcnt vmcnt(0)" ::: "memory");
    __builtin_amdgcn_sched_barrier(0);
    __builtin_amdgcn_s_barrier();

    f32x16 acc[2][2] = {};
#pragma unroll
    for (int ks = 0; ks < 4; ++ks) {
        const int p0 = ks * 4 + khalf * 2;
        i32x8 aF[2], bF[2];
#pragma unroll
        for (int rt = 0; rt < 2; ++rt)
            aF[rt] = ldsc(As, wr * 64 + rt * 32 + l31, p0);
#pragma unroll
        for (int ct = 0; ct < 2; ++ct)
            bF[ct] = ldsc(Bs, wc * 64 + ct * 32 + l31, p0);
        __builtin_amdgcn_s_setprio(1);
#pragma unroll
        for (int rt = 0; rt < 2; ++rt)
#pragma unroll
            for (int ct = 0; ct < 2; ++ct)
                acc[rt][ct] = __builtin_amdgcn_mfma_scale_f32_32x32x64_f8f6f4(
                    aF[rt], bF[ct], acc[rt][ct], 0, 0, 0, 127, 0, 127);
        __builtin_amdgcn_s_setprio(0);
    }

    // ---- epilogue: exp(s/16), fp8 encode, per-wave LDS transpose, Z sums ----
    __syncthreads();                               // all tile reads done
    char* wbuf = SMEM + wid * 5120;                // 64 rows x 80 B
    char* Pp = Pe8 + ((size_t)bh << 20);
    const int rowbase = it8 * 128 + wr * 64;
    const int colbase = jt8 * 128 + wc * 64;
    int vmv[2];
#pragma unroll
    for (int ct = 0; ct < 2; ++ct)
        vmv[ct] = vm[(b << 10) + colbase + ct * 32 + l31];
    float zacc[2][16] = {};
#pragma unroll
    for (int rt = 0; rt < 2; ++rt) {
#pragma unroll
        for (int ct = 0; ct < 2; ++ct) {
            const int col = colbase + ct * 32 + l31;
#pragma unroll
            for (int reg = 0; reg < 16; ++reg) {
                const int rin = (reg & 3) + 8 * (reg >> 2) + 4 * khalf;
                const int row = rowbase + rt * 32 + rin;
                float e = __expf(acc[rt][ct][reg] * 0.0625f);
                zacc[rt][reg] += (vmv[ct] && (col > row)) ? e : 0.f;
                wbuf[(rt * 32 + rin) * 80 + ct * 32 + l31] =
                    (char)(__builtin_amdgcn_cvt_pk_fp8_f32(e, e, 0, false) & 0xff);
            }
        }
    }
    // flush 64 rows x 64 B: 4 x (16B LDS read + 16B/lane coalesced store)
#pragma unroll
    for (int c = 0; c < 4; ++c) {
        const int rrow = c * 16 + (lane >> 2);
        uint4 v = *(const uint4*)&wbuf[rrow * 80 + (lane & 3) * 16];
        const int grow = rowbase + rrow;
        if (colbase + 63 > grow)
            *(uint4*)&Pp[(size_t)grow * 1024 + colbase + (lane & 3) * 16] = v;
    }
    // Z partials: reduce over 32 j-lanes, write slice jt8*2+wc
#pragma unroll
    for (int rt = 0; rt < 2; ++rt)
#pragma unroll
        for (int reg = 0; reg < 16; ++reg) {
            zacc[rt][reg] += __shfl_xor(zacc[rt][reg], 1);
            zacc[rt][reg] += __shfl_xor(zacc[rt][reg], 2);
            zacc[rt][reg] += __shfl_xor(zacc[rt][reg], 4);
            zacc[rt][reg] += __shfl_xor(zacc[rt][reg], 8);
            zacc[rt][reg] += __shfl_xor(zacc[rt][reg], 16);
        }
    if (l31 == 0) {                                // lanes 0 and 32 (khalf rows)
        float* Zs = Zp + (size_t)(jt8 * 2 + wc) * 32768 + bh * 1024;
#pragma unroll
        for (int rt = 0; rt < 2; ++rt)
#pragma unroll
            for (int reg = 0; reg < 16; ++reg) {
                const int rin = (reg & 3) + 8 * (reg >> 2) + 4 * khalf;
                Zs[rowbase + rt * 32 + rin] = zacc[rt][reg];
            }
    }
}

// ---- 4. k_final: parallel ec reduction + fp8 decode + logsum ----------------
__global__ LB void k_final(const char* __restrict__ Pe8, const int* __restrict__ vm,
                           const float* __restrict__ lgA, const float* __restrict__ Zp,
                           float* __restrict__ out) {
    __shared__ float ecs[4];
    const int blk = blockIdx.x;                    // b*1024 + i
    const int b = blk >> 10, i = blk & 1023;
    const int t = threadIdx.x;
    if (t < 64) {                                  // wave 0: 4 heads x 16 slices
        int h = t >> 4, sl = t & 15;
        int base = (b * 4 + h) * 1024 + i;
        float z = (sl >= ((i >> 7) << 1)) ? Zp[(size_t)sl * 32768 + base] : 0.f;
        z += __shfl_xor(z, 1); z += __shfl_xor(z, 2);
        z += __shfl_xor(z, 4); z += __shfl_xor(z, 8);
        if (sl == 0) {
            float lgv = lgA[blk * 4 + h];
            ecs[h] = (z > 0.f) ? __expf(lgv) / z : 0.f;
        }
    }
    __syncthreads();
    const int j0 = t * 4;
    float4 o = {-1.0e9f, -1.0e9f, -1.0e9f, -1.0e9f};
    if (j0 + 3 > i) {
        int4 v4 = *(const int4*)&vm[(b << 10) + j0];
        float a0 = 0.f, a1 = 0.f, a2 = 0.f, a3 = 0.f;
#pragma unroll
        for (int h = 0; h < 4; ++h) {
            unsigned p = *(const unsigned*)
                &Pe8[(((size_t)(b * 4 + h)) << 20) + ((size_t)i << 10) + j0];
            float ech = ecs[h];
            a0 += __builtin_amdgcn_cvt_f32_fp8((int)p, 0) * ech;
            a1 += __builtin_amdgcn_cvt_f32_fp8((int)p, 1) * ech;
            a2 += __builtin_amdgcn_cvt_f32_fp8((int)p, 2) * ech;
            a3 += __builtin_amdgcn_cvt_f32_fp8((int)p, 3) * ech;
        }
        o.x = (v4.x && (j0 + 0 > i)) ? __logf(a0) : -1.0e9f;
        o.y = (v4.y && (j0 + 1 > i)) ? __logf(a1) : -1.0e9f;
        o.z = (v4.z && (j0 + 2 > i)) ? __logf(a2) : -1.0e9f;
        o.w = (v4.w && (j0 + 3 > i)) ? __logf(a3) : -1.0e9f;
    }
    *(float4*)&out[((size_t)blk << 10) + j0] = o;
}

// ---------------------------------------------------------------------------
extern "C" void kernel_launch(void* const* d_in, const int* in_sizes, int n_in,
                              void* d_out, int out_size, void* d_ws, size_t ws_size,
                              hipStream_t stream) {
    const float* features = (const float*)d_in[0];
    const int*   vmask    = (const int*)d_in[1];
    const float* Wq       = (const float*)d_in[2];
    const float* bq       = (const float*)d_in[3];
    const float* Wk       = (const float*)d_in[4];
    const float* bk       = (const float*)d_in[5];
    const float* Wg       = (const float*)d_in[6];
    const float* bg       = (const float*)d_in[7];
    float* out = (float*)d_out;

    // ws carve (~52 MB). Pe8 (33.5 MB) overlaps X8+W8 (10.5 MB, dead pre-k_sc).
    char*  Pe8 = (char*)d_ws;                  // [32 bh][1024 i][1024 j] fp8
    char*  X8  = (char*)d_ws;                  // [8192][1024] fp8
    char*  W8  = X8 + 8388608;                 // [2048][1024] fp8 (x16)
    char*  Q8  = (char*)d_ws + 33554432;       // [32 bh][1024][256] fp8 (natural)
    char*  K8  = Q8 + 8388608;                 // [32 bh][1024][256] fp8
    float* lgA = (float*)(K8 + 8388608);       // [8192][4]
    float* Zp  = lgA + 32768;                  // [16 slice][32 bh][1024 i]

    k_prep2<<<4096, 256, 0, stream>>>(features, Wg, bg, Wq, Wk, X8, lgA, W8);
    k_gemm<<<256, 512, 0, stream>>>(X8, W8, bq, bk, Q8, K8);
    k_sc<<<1152, 256, 0, stream>>>(Q8, K8, vmask, Pe8, Zp);
    k_final<<<8192, 256, 0, stream>>>(Pe8, vmask, lgA, Zp, out);
}